// Round 2
// baseline (1303.824 us; speedup 1.0000x reference)
//
#include <hip/hip_runtime.h>
#include <hip/hip_bf16.h>
#include <math.h>

// ---------------------------------------------------------------------------
// DCGNN: dynamic-graph BiLSTM stock model.
// Pipeline:
//   prep       : pack/convert weights to bf16, fuse biases, compute pid/off
//   dn_beta    : gather adj from all_PP, E=exp(thresh(norm)), colsum S, A3=Beta.adj
//   lstm1      : BiLSTM layer1, fused input proj (K=224 packed), MFMA recurrence
//   gemm(gx2)  : h1 @ Wih1_fwd^T  (32768x768x384), bf16 out
//   lstm2f     : layer2 forward recurrence (K=192), emits n[:,0:192]
//   gemm(g2b)+gates : layer2 backward = single LSTM step -> n[:,192:384]
//   gemm chain : fWf1 -> G1 -> comb -> fWf2 -> G2 -> comb
//   final      : [n|n1|n2] @ W_out + b -> tanh
// Round-2 changes: (a) __syncthreads() after lstm1 LDS zero-init (t=0 race),
// (b) library-based sigmoid/tanh (no raw v_rcp chain), (c) softmax sums use
// bf16-rounded E for consistency with the MFMA E^T GEMM.
// ---------------------------------------------------------------------------

typedef __attribute__((ext_vector_type(4))) float f32x4;
typedef __attribute__((ext_vector_type(8))) short bf16x8;

__device__ __forceinline__ float sigm(float x) { return 1.0f / (1.0f + __expf(-x)); }
__device__ __forceinline__ float tanh_f(float x) { return tanhf(x); }
__device__ __forceinline__ __hip_bfloat16 fbf(float x) { return __float2bfloat16(x); }

// ---------------- prep: weight packing + pid/off ---------------------------
#define PA0 344064   // Bpack0  [2][768][224]
#define PA1 491520   // Whh1f   [768][192]
#define PA2 786432   // Wih1f   [768][384]
#define PA3 1081344  // Wih1b   [768][384]
#define PA4 1130496  // Wf1t    [128][384]
#define PA5 1146880  // Wf2t    [128][128]
#define PA6 1148416  // bias0   [2][768]
#define PA7 1149184  // bias1f  [768]
#define PA8 1149952  // bias1b  [768]
#define PA9 1150976  // pid/off [1024]

__global__ __launch_bounds__(256) void prep_kernel(
    const float* __restrict__ input, const float* __restrict__ theta,
    const float* __restrict__ W_ih0, const float* __restrict__ W_hh0,
    const float* __restrict__ b_ih0, const float* __restrict__ b_hh0,
    const float* __restrict__ W_ih1, const float* __restrict__ W_hh1,
    const float* __restrict__ b_ih1, const float* __restrict__ b_hh1,
    const float* __restrict__ W_agg1, const float* __restrict__ W_agg2,
    __hip_bfloat16* Bpack0, __hip_bfloat16* Whh1f, __hip_bfloat16* Wih1f,
    __hip_bfloat16* Wih1b, __hip_bfloat16* Wf1t, __hip_bfloat16* Wf2t,
    float* bias0, float* bias1f, float* bias1b, int* pid, int* offv)
{
    int idx = blockIdx.x * 256 + threadIdx.x;
    if (idx < PA0) {
        int dir = idx / (768 * 224); int rem = idx % (768 * 224);
        int gi = rem / 224; int k = rem % 224;
        float v = 0.0f;
        if (k < 192)       v = W_hh0[dir * 147456 + gi * 192 + k];
        else if (k < 208)  v = W_ih0[dir * 12288 + gi * 16 + (k - 192)];
        Bpack0[idx] = fbf(v);
    } else if (idx < PA1) {
        int l = idx - PA0; Whh1f[l] = fbf(W_hh1[l]);               // dir 0
    } else if (idx < PA2) {
        int l = idx - PA1; Wih1f[l] = fbf(W_ih1[l]);               // dir 0
    } else if (idx < PA3) {
        int l = idx - PA2; Wih1b[l] = fbf(W_ih1[294912 + l]);      // dir 1
    } else if (idx < PA4) {
        int l = idx - PA3; int o = l / 384, k = l % 384;
        Wf1t[l] = fbf(W_agg1[k * 128 + o]);
    } else if (idx < PA5) {
        int l = idx - PA4; int o = l / 128, k = l % 128;
        Wf2t[l] = fbf(W_agg2[k * 128 + o]);
    } else if (idx < PA6) {
        int l = idx - PA5; bias0[l] = b_ih0[l] + b_hh0[l];
    } else if (idx < PA7) {
        int l = idx - PA6; bias1f[l] = b_ih1[l] + b_hh1[l];
    } else if (idx < PA8) {
        int l = idx - PA7; bias1b[l] = b_ih1[768 + l] + b_hh1[768 + l];
    } else if (idx < PA9) {
        int l = idx - PA8;
        float th = theta[l];
        const float* xp = input + (size_t)l * 512;
        float x30 = xp[480], x31 = xp[496];
        int p0 = x30 > th ? 1 : (x30 < -th ? -1 : 0);
        int p1 = x31 > th ? 1 : (x31 < -th ? -1 : 0);
        pid[l] = (p0 + 1) * 3 + (p1 + 1);
        offv[l] = (p1 + 1) * 3;
    }
}

// ---------------- dynamic network: E^T, S, A3 ------------------------------
__global__ __launch_bounds__(256) void dnbeta_kernel(
    const float* __restrict__ PP, const int* __restrict__ pid,
    const int* __restrict__ offv, __hip_bfloat16* __restrict__ E_T,
    float* __restrict__ S, float* __restrict__ A3)
{
    int y = blockIdx.x; int tid = threadIdx.x;
    int offy = offv[y];
    float sa = 0.f, p0 = 0.f, p1 = 0.f, p2 = 0.f;
    for (int xx = tid; xx < 1024; xx += 256) {
        size_t base = ((size_t)xx * 1024 + y) * 81 + pid[xx] * 9 + offy;
        float a0 = PP[base], a1 = PP[base + 1], a2 = PP[base + 2];
        float nr = sqrtf(a0 * a0 + a1 * a1 + a2 * a2);
        float bb = nr > 0.38f ? nr : 0.0f;
        float e = __expf(bb);
        __hip_bfloat16 eb = fbf(e);
        float ef = __bfloat162float(eb);      // accumulate what the GEMM will see
        E_T[(size_t)y * 1024 + xx] = eb;
        sa += ef; p0 += ef * a0; p1 += ef * a1; p2 += ef * a2;
    }
    __shared__ float red[4][256];
    red[0][tid] = sa; red[1][tid] = p0; red[2][tid] = p1; red[3][tid] = p2;
    __syncthreads();
    for (int st = 128; st > 0; st >>= 1) {
        if (tid < st) {
            red[0][tid] += red[0][tid + st]; red[1][tid] += red[1][tid + st];
            red[2][tid] += red[2][tid + st]; red[3][tid] += red[3][tid + st];
        }
        __syncthreads();
    }
    if (tid == 0) {
        float s_ = red[0][0];
        S[y] = s_;
        float inv = 1.0f / s_;
        A3[y * 3 + 0] = red[1][0] * inv;
        A3[y * 3 + 1] = red[2][0] * inv;
        A3[y * 3 + 2] = red[3][0] * inv;
    }
}

// ---------------- LSTM layer 1 (fused input proj, K=224) -------------------
// grid (32, 2): 32 stocks/block, dir in y. Wave w owns j-slice [48w,48w+48)
// across all 4 gates -> gate math fully in-lane.
__global__ __launch_bounds__(256) void lstm1_kernel(
    const float* __restrict__ x,            // [1024][32][16]
    const __hip_bfloat16* __restrict__ Bp,  // [2][768][224] packed [Whh|Wih|0]
    const float* __restrict__ bias,         // [2][768]
    __hip_bfloat16* __restrict__ h1)        // [1024][32][384]
{
    const int dir = blockIdx.y;
    const int n0 = blockIdx.x * 32;
    const int tid = threadIdx.x;
    const int wv = tid >> 6, lane = tid & 63;
    const int col = lane & 15, quad = lane >> 4;

    __shared__ __hip_bfloat16 hA[32][232];   // stride 232: 2-way LDS aliasing (free)

    for (int i = tid; i < 32 * 232; i += 256) ((__hip_bfloat16*)hA)[i] = fbf(0.0f);
    __syncthreads();                          // RACE FIX: order zero-init vs t=0 x-stage

    float brg[4][3];
#pragma unroll
    for (int g = 0; g < 4; ++g)
#pragma unroll
        for (int c = 0; c < 3; ++c)
            brg[g][c] = bias[dir * 768 + 192 * g + 48 * wv + 16 * c + col];

    const __hip_bfloat16* Bbase = Bp + (size_t)dir * 768 * 224;

    float cst[2][3][4];
#pragma unroll
    for (int m = 0; m < 2; ++m)
#pragma unroll
        for (int c = 0; c < 3; ++c)
#pragma unroll
            for (int r = 0; r < 4; ++r) cst[m][c][r] = 0.f;

    for (int t = 0; t < 32; ++t) {
        const int tt = dir ? (31 - t) : t;
        {   // stage x_t into A-tile cols 192..207 (208..223 stay zero)
            int s = tid >> 3;
            int i0 = (tid & 7) * 2;
            const float* xp = x + ((size_t)(n0 + s) * 32 + tt) * 16 + i0;
            hA[s][192 + i0] = fbf(xp[0]);
            hA[s][192 + i0 + 1] = fbf(xp[1]);
        }
        __syncthreads();

        f32x4 acc[2][4][3];
#pragma unroll
        for (int m = 0; m < 2; ++m)
#pragma unroll
            for (int g = 0; g < 4; ++g)
#pragma unroll
                for (int c = 0; c < 3; ++c) {
                    f32x4 v; v[0] = brg[g][c]; v[1] = brg[g][c]; v[2] = brg[g][c]; v[3] = brg[g][c];
                    acc[m][g][c] = v;
                }
#pragma unroll
        for (int kf = 0; kf < 7; ++kf) {
            bf16x8 a0 = *(const bf16x8*)&hA[col][kf * 32 + quad * 8];
            bf16x8 a1 = *(const bf16x8*)&hA[16 + col][kf * 32 + quad * 8];
#pragma unroll
            for (int g = 0; g < 4; ++g)
#pragma unroll
                for (int c = 0; c < 3; ++c) {
                    const __hip_bfloat16* bp =
                        Bbase + (size_t)(192 * g + 48 * wv + 16 * c + col) * 224 + kf * 32 + quad * 8;
                    bf16x8 b = *(const bf16x8*)bp;
                    acc[0][g][c] = __builtin_amdgcn_mfma_f32_16x16x32_bf16(a0, b, acc[0][g][c], 0, 0, 0);
                    acc[1][g][c] = __builtin_amdgcn_mfma_f32_16x16x32_bf16(a1, b, acc[1][g][c], 0, 0, 0);
                }
        }
        __syncthreads();
#pragma unroll
        for (int m = 0; m < 2; ++m)
#pragma unroll
            for (int r = 0; r < 4; ++r) {
                int s = m * 16 + quad * 4 + r;
#pragma unroll
                for (int c = 0; c < 3; ++c) {
                    float gi_ = acc[m][0][c][r];
                    float gf_ = acc[m][1][c][r];
                    float gg_ = acc[m][2][c][r];
                    float go_ = acc[m][3][c][r];
                    float si = sigm(gi_), sf = sigm(gf_), tg = tanh_f(gg_), so = sigm(go_);
                    float cs = sf * cst[m][c][r] + si * tg;
                    cst[m][c][r] = cs;
                    float h = so * tanh_f(cs);
                    __hip_bfloat16 hb = fbf(h);
                    int j = 48 * wv + 16 * c + col;
                    hA[s][j] = hb;
                    h1[((size_t)(n0 + s) * 32 + tt) * 384 + dir * 192 + j] = hb;
                }
            }
    }
}

// ---------------- LSTM layer 2 forward (K=192, gx2 precomputed) ------------
__global__ __launch_bounds__(256) void lstm2f_kernel(
    const __hip_bfloat16* __restrict__ gx2,  // [32768][768], row = n*32+t
    const __hip_bfloat16* __restrict__ Whh,  // [768][192]
    __hip_bfloat16* __restrict__ n_bf,       // [1024][384]
    float* __restrict__ n_f32)               // [1024][384]
{
    const int n0 = blockIdx.x * 32;
    const int tid = threadIdx.x;
    const int wv = tid >> 6, lane = tid & 63;
    const int col = lane & 15, quad = lane >> 4;

    __shared__ __hip_bfloat16 hA[32][200];   // stride 200: 2-way aliasing (free)

    for (int i = tid; i < 32 * 200; i += 256) ((__hip_bfloat16*)hA)[i] = fbf(0.0f);

    float cst[2][3][4];
#pragma unroll
    for (int m = 0; m < 2; ++m)
#pragma unroll
        for (int c = 0; c < 3; ++c)
#pragma unroll
            for (int r = 0; r < 4; ++r) cst[m][c][r] = 0.f;

    for (int t = 0; t < 32; ++t) {
        __syncthreads();   // orders zero-init / previous h-writes before reads

        f32x4 acc[2][4][3];
#pragma unroll
        for (int m = 0; m < 2; ++m)
#pragma unroll
            for (int g = 0; g < 4; ++g)
#pragma unroll
                for (int c = 0; c < 3; ++c) {
                    f32x4 v;
#pragma unroll
                    for (int r = 0; r < 4; ++r)
                        v[r] = __bfloat162float(
                            gx2[((size_t)(n0 + m * 16 + quad * 4 + r) * 32 + t) * 768 +
                                192 * g + 48 * wv + 16 * c + col]);
                    acc[m][g][c] = v;
                }
#pragma unroll
        for (int kf = 0; kf < 6; ++kf) {
            bf16x8 a0 = *(const bf16x8*)&hA[col][kf * 32 + quad * 8];
            bf16x8 a1 = *(const bf16x8*)&hA[16 + col][kf * 32 + quad * 8];
#pragma unroll
            for (int g = 0; g < 4; ++g)
#pragma unroll
                for (int c = 0; c < 3; ++c) {
                    const __hip_bfloat16* bp =
                        Whh + (size_t)(192 * g + 48 * wv + 16 * c + col) * 192 + kf * 32 + quad * 8;
                    bf16x8 b = *(const bf16x8*)bp;
                    acc[0][g][c] = __builtin_amdgcn_mfma_f32_16x16x32_bf16(a0, b, acc[0][g][c], 0, 0, 0);
                    acc[1][g][c] = __builtin_amdgcn_mfma_f32_16x16x32_bf16(a1, b, acc[1][g][c], 0, 0, 0);
                }
        }
        __syncthreads();
#pragma unroll
        for (int m = 0; m < 2; ++m)
#pragma unroll
            for (int r = 0; r < 4; ++r) {
                int s = m * 16 + quad * 4 + r;
#pragma unroll
                for (int c = 0; c < 3; ++c) {
                    float gi_ = acc[m][0][c][r];
                    float gf_ = acc[m][1][c][r];
                    float gg_ = acc[m][2][c][r];
                    float go_ = acc[m][3][c][r];
                    float si = sigm(gi_), sf = sigm(gf_), tg = tanh_f(gg_), so = sigm(go_);
                    float cs = sf * cst[m][c][r] + si * tg;
                    cst[m][c][r] = cs;
                    float h = so * tanh_f(cs);
                    __hip_bfloat16 hb = fbf(h);
                    int j = 48 * wv + 16 * c + col;
                    hA[s][j] = hb;
                    if (t == 31) {
                        n_f32[(size_t)(n0 + s) * 384 + j] = h;
                        n_bf[(size_t)(n0 + s) * 384 + j] = hb;
                    }
                }
            }
    }
}

// ---------------- generic bf16 MFMA GEMM -----------------------------------
// C[M][N] = A[M][K] @ B[N][K]^T (+bias[col]); block tile 128Mx64N, wave 32Mx64N.
// flags: bit0 = bf16 out, bit1 = store transposed (C^T at [col][row], ldc=M-dim)
__global__ __launch_bounds__(256) void gemm_kernel(
    const __hip_bfloat16* __restrict__ A, long lda,
    const __hip_bfloat16* __restrict__ B, long ldb,
    const float* __restrict__ bias,
    void* __restrict__ C, long ldc, int K, int flags)
{
    const int tid = threadIdx.x;
    const int wv = tid >> 6, lane = tid & 63;
    const int col = lane & 15, quad = lane >> 4;
    const long m0 = (long)blockIdx.y * 128 + wv * 32;
    const long n0 = (long)blockIdx.x * 64;

    const __hip_bfloat16* Ap = A + (m0 + col) * lda + quad * 8;
    const __hip_bfloat16* Ap2 = Ap + 16 * lda;
    const __hip_bfloat16* Bp = B + (n0 + col) * ldb + quad * 8;

    f32x4 acc[2][4];
#pragma unroll
    for (int mt = 0; mt < 2; ++mt)
#pragma unroll
        for (int nt = 0; nt < 4; ++nt) acc[mt][nt] = (f32x4)0.0f;

#pragma unroll 4
    for (int k = 0; k < K; k += 32) {
        bf16x8 a0 = *(const bf16x8*)(Ap + k);
        bf16x8 a1 = *(const bf16x8*)(Ap2 + k);
#pragma unroll
        for (int nt = 0; nt < 4; ++nt) {
            bf16x8 b = *(const bf16x8*)(Bp + (long)nt * 16 * ldb + k);
            acc[0][nt] = __builtin_amdgcn_mfma_f32_16x16x32_bf16(a0, b, acc[0][nt], 0, 0, 0);
            acc[1][nt] = __builtin_amdgcn_mfma_f32_16x16x32_bf16(a1, b, acc[1][nt], 0, 0, 0);
        }
    }
#pragma unroll
    for (int mt = 0; mt < 2; ++mt)
#pragma unroll
        for (int nt = 0; nt < 4; ++nt)
#pragma unroll
            for (int r = 0; r < 4; ++r) {
                long row = m0 + mt * 16 + quad * 4 + r;
                long cc = n0 + nt * 16 + col;
                float v = acc[mt][nt][r] + (bias ? bias[cc] : 0.0f);
                if (flags & 2) {
                    if (flags & 1) ((__hip_bfloat16*)C)[cc * ldc + row] = fbf(v);
                    else           ((float*)C)[cc * ldc + row] = v;
                } else {
                    if (flags & 1) ((__hip_bfloat16*)C)[row * ldc + cc] = fbf(v);
                    else           ((float*)C)[row * ldc + cc] = v;
                }
            }
}

// ---------------- layer-2 backward single-step gates -----------------------
__global__ __launch_bounds__(256) void bwdgates_kernel(
    const float* __restrict__ g2b, float* __restrict__ n_f32,
    __hip_bfloat16* __restrict__ n_bf)
{
    int idx = blockIdx.x * 256 + threadIdx.x;   // < 196608
    int n = idx / 192, j = idx % 192;
    float gi_ = g2b[(size_t)n * 768 + j];
    float gg_ = g2b[(size_t)n * 768 + 384 + j];
    float go_ = g2b[(size_t)n * 768 + 576 + j];
    float c = sigm(gi_) * tanh_f(gg_);          // f-term has c0=0
    float h = sigm(go_) * tanh_f(c);
    n_f32[(size_t)n * 384 + 192 + j] = h;
    n_bf[(size_t)n * 384 + 192 + j] = fbf(h);
}

// ---------------- combine: n_k = G/S + A3 @ Wa + b --------------------------
__global__ __launch_bounds__(128) void comb_kernel(
    const float* __restrict__ G, const float* __restrict__ S,
    const float* __restrict__ A3, const float* __restrict__ Wa,   // [3][128]
    const float* __restrict__ bb, float* __restrict__ out_f,
    __hip_bfloat16* __restrict__ out_b)
{
    int y = blockIdx.x, o = threadIdx.x;
    float v = G[(size_t)y * 128 + o] / S[y]
            + A3[y * 3 + 0] * Wa[o] + A3[y * 3 + 1] * Wa[128 + o] + A3[y * 3 + 2] * Wa[256 + o]
            + bb[o];
    out_f[(size_t)y * 128 + o] = v;
    if (out_b) out_b[(size_t)y * 128 + o] = fbf(v);
}

// ---------------- final head -----------------------------------------------
__global__ __launch_bounds__(256) void final_kernel(
    const float* __restrict__ n_, const float* __restrict__ n1,
    const float* __restrict__ n2, const float* __restrict__ Wout,
    const float* __restrict__ bout, float* __restrict__ out)
{
    int y = blockIdx.x * 256 + threadIdx.x;
    if (y >= 1024) return;
    float a0 = bout[0], a1 = bout[1];
    for (int k = 0; k < 384; ++k) {
        float v = n_[(size_t)y * 384 + k];
        a0 += v * Wout[k * 2]; a1 += v * Wout[k * 2 + 1];
    }
    for (int k = 0; k < 128; ++k) {
        float v = n1[(size_t)y * 128 + k];
        a0 += v * Wout[(384 + k) * 2]; a1 += v * Wout[(384 + k) * 2 + 1];
    }
    for (int k = 0; k < 128; ++k) {
        float v = n2[(size_t)y * 128 + k];
        a0 += v * Wout[(512 + k) * 2]; a1 += v * Wout[(512 + k) * 2 + 1];
    }
    out[y * 2] = tanh_f(a0);
    out[y * 2 + 1] = tanh_f(a1);
}

// ---------------------------------------------------------------------------
extern "C" void kernel_launch(void* const* d_in, const int* in_sizes, int n_in,
                              void* d_out, int out_size, void* d_ws, size_t ws_size,
                              hipStream_t stream)
{
    const float* input  = (const float*)d_in[0];
    const float* theta  = (const float*)d_in[1];
    const float* all_PP = (const float*)d_in[2];
    const float* W_ih0  = (const float*)d_in[3];
    const float* W_hh0  = (const float*)d_in[4];
    const float* b_ih0  = (const float*)d_in[5];
    const float* b_hh0  = (const float*)d_in[6];
    const float* W_ih1  = (const float*)d_in[7];
    const float* W_hh1  = (const float*)d_in[8];
    const float* b_ih1  = (const float*)d_in[9];
    const float* b_hh1  = (const float*)d_in[10];
    const float* W_agg1 = (const float*)d_in[11];
    const float* b_agg1 = (const float*)d_in[12];
    const float* W_agg2 = (const float*)d_in[13];
    const float* b_agg2 = (const float*)d_in[14];
    const float* W_out  = (const float*)d_in[15];
    const float* b_out  = (const float*)d_in[16];
    float* out = (float*)d_out;

    char* ws = (char*)d_ws;
    size_t off = 0;
    auto alloc = [&](size_t bytes) -> char* {
        char* p = ws + off;
        off = (off + bytes + 255) & ~(size_t)255;
        return p;
    };
    __hip_bfloat16* Bpack0 = (__hip_bfloat16*)alloc(344064 * 2);
    __hip_bfloat16* Whh1f  = (__hip_bfloat16*)alloc(147456 * 2);
    __hip_bfloat16* Wih1f  = (__hip_bfloat16*)alloc(294912 * 2);
    __hip_bfloat16* Wih1b  = (__hip_bfloat16*)alloc(294912 * 2);
    __hip_bfloat16* Wf1t   = (__hip_bfloat16*)alloc(49152 * 2);
    __hip_bfloat16* Wf2t   = (__hip_bfloat16*)alloc(16384 * 2);
    float* bias0  = (float*)alloc(1536 * 4);
    float* bias1f = (float*)alloc(768 * 4);
    float* bias1b = (float*)alloc(768 * 4);
    int* pid  = (int*)alloc(1024 * 4);
    int* offv = (int*)alloc(1024 * 4);
    __hip_bfloat16* E_T = (__hip_bfloat16*)alloc((size_t)1024 * 1024 * 2);
    float* Sv  = (float*)alloc(1024 * 4);
    float* A3v = (float*)alloc(1024 * 3 * 4);
    __hip_bfloat16* h1  = (__hip_bfloat16*)alloc((size_t)1024 * 32 * 384 * 2);
    __hip_bfloat16* gx2 = (__hip_bfloat16*)alloc((size_t)32768 * 768 * 2);
    float* g2b = (float*)alloc((size_t)1024 * 768 * 4);
    float* n_f32 = (float*)alloc((size_t)1024 * 384 * 4);
    __hip_bfloat16* n_bf = (__hip_bfloat16*)alloc((size_t)1024 * 384 * 2);
    __hip_bfloat16* fWf1t = (__hip_bfloat16*)alloc((size_t)128 * 1024 * 2);
    float* G1 = (float*)alloc((size_t)1024 * 128 * 4);
    float* n1_f32 = (float*)alloc((size_t)1024 * 128 * 4);
    __hip_bfloat16* n1_bf = (__hip_bfloat16*)alloc((size_t)1024 * 128 * 2);
    __hip_bfloat16* fWf2t = (__hip_bfloat16*)alloc((size_t)128 * 1024 * 2);
    float* G2 = (float*)alloc((size_t)1024 * 128 * 4);
    float* n2_f32 = (float*)alloc((size_t)1024 * 128 * 4);
    (void)ws_size; (void)in_sizes; (void)n_in; (void)out_size;

    prep_kernel<<<(PA9 + 255) / 256, 256, 0, stream>>>(
        input, theta, W_ih0, W_hh0, b_ih0, b_hh0, W_ih1, W_hh1, b_ih1, b_hh1,
        W_agg1, W_agg2, Bpack0, Whh1f, Wih1f, Wih1b, Wf1t, Wf2t,
        bias0, bias1f, bias1b, pid, offv);

    dnbeta_kernel<<<1024, 256, 0, stream>>>(all_PP, pid, offv, E_T, Sv, A3v);

    lstm1_kernel<<<dim3(32, 2), 256, 0, stream>>>(input, Bpack0, bias0, h1);

    // gx2 = h1 @ Wih1_fwd^T + bias1f   (M=32768, N=768, K=384) -> bf16
    gemm_kernel<<<dim3(12, 256), 256, 0, stream>>>(h1, 384L, Wih1f, 384L, bias1f,
                                                   gx2, 768L, 384, 1);

    lstm2f_kernel<<<32, 256, 0, stream>>>(gx2, Whh1f, n_bf, n_f32);

    // layer2 bwd single step: g2b = h1[:,31,:] @ Wih1_bwd^T + bias1b
    gemm_kernel<<<dim3(12, 8), 256, 0, stream>>>(h1 + 31 * 384, 12288L, Wih1b, 384L,
                                                 bias1b, g2b, 768L, 384, 0);
    bwdgates_kernel<<<768, 256, 0, stream>>>(g2b, n_f32, n_bf);

    // fWf1^T = (n @ Wf1)^T   (M=1024, N=128, K=384) -> bf16 transposed [128][1024]
    gemm_kernel<<<dim3(2, 8), 256, 0, stream>>>(n_bf, 384L, Wf1t, 384L, nullptr,
                                                fWf1t, 1024L, 384, 3);
    // G1 = E^T @ fWf1        (M=1024, N=128, K=1024)
    gemm_kernel<<<dim3(2, 8), 256, 0, stream>>>(E_T, 1024L, fWf1t, 1024L, nullptr,
                                                G1, 128L, 1024, 0);
    comb_kernel<<<1024, 128, 0, stream>>>(G1, Sv, A3v, W_agg1 + 384 * 128, b_agg1,
                                          n1_f32, n1_bf);

    // fWf2^T = (n1 @ Wf2)^T  (M=1024, N=128, K=128)
    gemm_kernel<<<dim3(2, 8), 256, 0, stream>>>(n1_bf, 128L, Wf2t, 128L, nullptr,
                                                fWf2t, 1024L, 128, 3);
    // G2 = E^T @ fWf2
    gemm_kernel<<<dim3(2, 8), 256, 0, stream>>>(E_T, 1024L, fWf2t, 1024L, nullptr,
                                                G2, 128L, 1024, 0);
    comb_kernel<<<1024, 128, 0, stream>>>(G2, Sv, A3v, W_agg2 + 128 * 128, b_agg2,
                                          n2_f32, nullptr);

    final_kernel<<<4, 256, 0, stream>>>(n_f32, n1_f32, n2_f32, W_out, b_out, out);
}

// Round 3
// 910.833 us; speedup vs baseline: 1.4315x; 1.4315x over previous
//
#include <hip/hip_runtime.h>
#include <hip/hip_bf16.h>
#include <math.h>

// ---------------------------------------------------------------------------
// DCGNN: dynamic-graph BiLSTM stock model.
// Round-3: weight-stationary LSTM recurrences.
//   lstm1: 768 thr/block, 12 waves x 16 hidden units, Whh-slice in VGPRs
//          (96 regs), 16 stocks/block -> grid (64,2). x-proj fused (K=224).
//   lstm2f: same structure, gate inputs gx2 stored [t][col][n] for 8B loads.
//   Gate math: v_exp + v_rcp forms (denominator>=1 -> NaN-free).
// ---------------------------------------------------------------------------

typedef __attribute__((ext_vector_type(4))) float f32x4;
typedef __attribute__((ext_vector_type(8))) short bf16x8;

__device__ __forceinline__ float sigm(float x) { return 1.0f / (1.0f + __expf(-x)); }
__device__ __forceinline__ float tanh_f(float x) { return tanhf(x); }
// fast forms for the hot recurrence kernels (rcp args >= 1 -> never NaN)
__device__ __forceinline__ float sigm_r(float x) {
    return __builtin_amdgcn_rcpf(1.0f + __expf(-x));
}
__device__ __forceinline__ float tanh_r(float x) {
    float e = __expf(2.0f * x);                    // finite or +inf
    return 1.0f - 2.0f * __builtin_amdgcn_rcpf(e + 1.0f);
}
__device__ __forceinline__ __hip_bfloat16 fbf(float x) { return __float2bfloat16(x); }
__device__ __forceinline__ float bf2f(unsigned short u) {
    return __uint_as_float(((unsigned)u) << 16);
}

// ---------------- prep: weight packing + pid/off ---------------------------
#define PA0 344064   // Bpack0  [2][768][224]
#define PA1 491520   // Whh1f   [768][192]
#define PA2 786432   // Wih1f   [768][384]
#define PA3 1081344  // Wih1b   [768][384]
#define PA4 1130496  // Wf1t    [128][384]
#define PA5 1146880  // Wf2t    [128][128]
#define PA6 1148416  // bias0   [2][768]
#define PA7 1149184  // bias1f  [768]
#define PA8 1149952  // bias1b  [768]
#define PA9 1150976  // pid/off [1024]

__global__ __launch_bounds__(256) void prep_kernel(
    const float* __restrict__ input, const float* __restrict__ theta,
    const float* __restrict__ W_ih0, const float* __restrict__ W_hh0,
    const float* __restrict__ b_ih0, const float* __restrict__ b_hh0,
    const float* __restrict__ W_ih1, const float* __restrict__ W_hh1,
    const float* __restrict__ b_ih1, const float* __restrict__ b_hh1,
    const float* __restrict__ W_agg1, const float* __restrict__ W_agg2,
    __hip_bfloat16* Bpack0, __hip_bfloat16* Whh1f, __hip_bfloat16* Wih1f,
    __hip_bfloat16* Wih1b, __hip_bfloat16* Wf1t, __hip_bfloat16* Wf2t,
    float* bias0, float* bias1f, float* bias1b, int* pid, int* offv)
{
    int idx = blockIdx.x * 256 + threadIdx.x;
    if (idx < PA0) {
        int dir = idx / (768 * 224); int rem = idx % (768 * 224);
        int gi = rem / 224; int k = rem % 224;
        float v = 0.0f;
        if (k < 192)       v = W_hh0[dir * 147456 + gi * 192 + k];
        else if (k < 208)  v = W_ih0[dir * 12288 + gi * 16 + (k - 192)];
        Bpack0[idx] = fbf(v);
    } else if (idx < PA1) {
        int l = idx - PA0; Whh1f[l] = fbf(W_hh1[l]);               // dir 0
    } else if (idx < PA2) {
        int l = idx - PA1; Wih1f[l] = fbf(W_ih1[l]);               // dir 0
    } else if (idx < PA3) {
        int l = idx - PA2; Wih1b[l] = fbf(W_ih1[294912 + l]);      // dir 1
    } else if (idx < PA4) {
        int l = idx - PA3; int o = l / 384, k = l % 384;
        Wf1t[l] = fbf(W_agg1[k * 128 + o]);
    } else if (idx < PA5) {
        int l = idx - PA4; int o = l / 128, k = l % 128;
        Wf2t[l] = fbf(W_agg2[k * 128 + o]);
    } else if (idx < PA6) {
        int l = idx - PA5; bias0[l] = b_ih0[l] + b_hh0[l];
    } else if (idx < PA7) {
        int l = idx - PA6; bias1f[l] = b_ih1[l] + b_hh1[l];
    } else if (idx < PA8) {
        int l = idx - PA7; bias1b[l] = b_ih1[768 + l] + b_hh1[768 + l];
    } else if (idx < PA9) {
        int l = idx - PA8;
        float th = theta[l];
        const float* xp = input + (size_t)l * 512;
        float x30 = xp[480], x31 = xp[496];
        int p0 = x30 > th ? 1 : (x30 < -th ? -1 : 0);
        int p1 = x31 > th ? 1 : (x31 < -th ? -1 : 0);
        pid[l] = (p0 + 1) * 3 + (p1 + 1);
        offv[l] = (p1 + 1) * 3;
    }
}

// ---------------- dynamic network: E^T, S, A3 ------------------------------
__global__ __launch_bounds__(256) void dnbeta_kernel(
    const float* __restrict__ PP, const int* __restrict__ pid,
    const int* __restrict__ offv, __hip_bfloat16* __restrict__ E_T,
    float* __restrict__ S, float* __restrict__ A3)
{
    int y = blockIdx.x; int tid = threadIdx.x;
    int offy = offv[y];
    float sa = 0.f, p0 = 0.f, p1 = 0.f, p2 = 0.f;
    for (int xx = tid; xx < 1024; xx += 256) {
        size_t base = ((size_t)xx * 1024 + y) * 81 + pid[xx] * 9 + offy;
        float a0 = PP[base], a1 = PP[base + 1], a2 = PP[base + 2];
        float nr = sqrtf(a0 * a0 + a1 * a1 + a2 * a2);
        float bb = nr > 0.38f ? nr : 0.0f;
        float e = __expf(bb);
        __hip_bfloat16 eb = fbf(e);
        float ef = __bfloat162float(eb);      // accumulate what the GEMM will see
        E_T[(size_t)y * 1024 + xx] = eb;
        sa += ef; p0 += ef * a0; p1 += ef * a1; p2 += ef * a2;
    }
    __shared__ float red[4][256];
    red[0][tid] = sa; red[1][tid] = p0; red[2][tid] = p1; red[3][tid] = p2;
    __syncthreads();
    for (int st = 128; st > 0; st >>= 1) {
        if (tid < st) {
            red[0][tid] += red[0][tid + st]; red[1][tid] += red[1][tid + st];
            red[2][tid] += red[2][tid + st]; red[3][tid] += red[3][tid + st];
        }
        __syncthreads();
    }
    if (tid == 0) {
        float s_ = red[0][0];
        S[y] = s_;
        float inv = 1.0f / s_;
        A3[y * 3 + 0] = red[1][0] * inv;
        A3[y * 3 + 1] = red[2][0] * inv;
        A3[y * 3 + 2] = red[3][0] * inv;
    }
}

// ---------------- LSTM layer 1 (weight-stationary, fused x-proj) -----------
// grid (64, 2): 16 stocks/block. 12 waves; wave W owns hidden units
// [16W,16W+16) across all 4 gates (in-lane gate math). Whh-slice of each
// wave lives in VGPRs (6 kf x 4 g x 4 regs = 96 VGPR), loaded ONCE.
__global__ __launch_bounds__(768) void lstm1_kernel(
    const float* __restrict__ x,            // [1024][32][16]
    const __hip_bfloat16* __restrict__ Bp,  // [2][768][224] packed [Whh|Wih|0]
    const float* __restrict__ bias,         // [2][768]
    __hip_bfloat16* __restrict__ h1)        // [1024][32][384]
{
    const int dir = blockIdx.y;
    const int n0 = blockIdx.x * 16;
    const int tid = threadIdx.x;
    const int W = tid >> 6, lane = tid & 63;
    const int col = lane & 15, quad = lane >> 4;

    __shared__ __hip_bfloat16 hA[16][232];   // cols 0..191 h, 192..207 x, 208..223 zero

    for (int i = tid; i < 16 * 232; i += 768) ((__hip_bfloat16*)hA)[i] = fbf(0.0f);

    const __hip_bfloat16* Bbase = Bp + (size_t)dir * 768 * 224;
    int rw[4];
    float brg[4];
    bf16x8 Bh[6][4];
#pragma unroll
    for (int g = 0; g < 4; ++g) {
        rw[g] = 192 * g + 16 * W + col;
        brg[g] = bias[dir * 768 + rw[g]];
#pragma unroll
        for (int kf = 0; kf < 6; ++kf)
            Bh[kf][g] = *(const bf16x8*)(Bbase + (size_t)rw[g] * 224 + kf * 32 + quad * 8);
    }

    float cst[4] = {0.f, 0.f, 0.f, 0.f};
    __syncthreads();

#pragma unroll 1
    for (int t = 0; t < 32; ++t) {
        const int tt = dir ? (31 - t) : t;
        if (tid < 256) {   // stage x_t into cols 192..207
            int s = tid >> 4, i = tid & 15;
            hA[s][192 + i] = fbf(x[((size_t)(n0 + s) * 32 + tt) * 16 + i]);
        }
        __syncthreads();   // h(t-1) writes + x stage visible

        f32x4 acc[4];
#pragma unroll
        for (int g = 0; g < 4; ++g) {
            f32x4 v; v[0] = brg[g]; v[1] = brg[g]; v[2] = brg[g]; v[3] = brg[g];
            acc[g] = v;
        }
#pragma unroll
        for (int kf = 0; kf < 6; ++kf) {
            bf16x8 a = *(const bf16x8*)&hA[col][kf * 32 + quad * 8];
#pragma unroll
            for (int g = 0; g < 4; ++g)
                acc[g] = __builtin_amdgcn_mfma_f32_16x16x32_bf16(a, Bh[kf][g], acc[g], 0, 0, 0);
        }
        {   // x-projection slice (cols 192..223; 208..223 are zeros)
            bf16x8 a6 = *(const bf16x8*)&hA[col][192 + quad * 8];
#pragma unroll
            for (int g = 0; g < 4; ++g) {
                bf16x8 bx = *(const bf16x8*)(Bbase + (size_t)rw[g] * 224 + 192 + quad * 8);
                acc[g] = __builtin_amdgcn_mfma_f32_16x16x32_bf16(a6, bx, acc[g], 0, 0, 0);
            }
        }
        __syncthreads();   // all MFMA reads done before h(t) writes

#pragma unroll
        for (int r = 0; r < 4; ++r) {
            float si = sigm_r(acc[0][r]);
            float sf = sigm_r(acc[1][r]);
            float tg = tanh_r(acc[2][r]);
            float so = sigm_r(acc[3][r]);
            float cs = sf * cst[r] + si * tg;
            cst[r] = cs;
            float h = so * tanh_r(cs);
            __hip_bfloat16 hb = fbf(h);
            int s = quad * 4 + r;
            int j = 16 * W + col;
            hA[s][j] = hb;
            h1[((size_t)(n0 + s) * 32 + tt) * 384 + dir * 192 + j] = hb;
        }
    }
}

// ---------------- LSTM layer 2 forward (weight-stationary) -----------------
// gx layout: [t][768 col][1024 n] bf16 -> per-gate 8B vector acc-init loads.
__global__ __launch_bounds__(768) void lstm2f_kernel(
    const __hip_bfloat16* __restrict__ gx,   // [32][768][1024]
    const __hip_bfloat16* __restrict__ Whh,  // [768][192]
    __hip_bfloat16* __restrict__ n_bf,       // [1024][384]
    float* __restrict__ n_f32)               // [1024][384]
{
    const int n0 = blockIdx.x * 16;
    const int tid = threadIdx.x;
    const int W = tid >> 6, lane = tid & 63;
    const int col = lane & 15, quad = lane >> 4;

    __shared__ __hip_bfloat16 hA[16][200];

    for (int i = tid; i < 16 * 200; i += 768) ((__hip_bfloat16*)hA)[i] = fbf(0.0f);

    int rw[4];
    bf16x8 Bh[6][4];
#pragma unroll
    for (int g = 0; g < 4; ++g) {
        rw[g] = 192 * g + 16 * W + col;
#pragma unroll
        for (int kf = 0; kf < 6; ++kf)
            Bh[kf][g] = *(const bf16x8*)(Whh + (size_t)rw[g] * 192 + kf * 32 + quad * 8);
    }

    float cst[4] = {0.f, 0.f, 0.f, 0.f};
    __syncthreads();

#pragma unroll 1
    for (int t = 0; t < 32; ++t) {
        f32x4 acc[4];
#pragma unroll
        for (int g = 0; g < 4; ++g) {
            const ushort4 u = *(const ushort4*)((const unsigned short*)gx +
                (size_t)t * 786432 + (size_t)rw[g] * 1024 + n0 + quad * 4);
            f32x4 v; v[0] = bf2f(u.x); v[1] = bf2f(u.y); v[2] = bf2f(u.z); v[3] = bf2f(u.w);
            acc[g] = v;
        }
        __syncthreads();   // h(t-1) writes visible

#pragma unroll
        for (int kf = 0; kf < 6; ++kf) {
            bf16x8 a = *(const bf16x8*)&hA[col][kf * 32 + quad * 8];
#pragma unroll
            for (int g = 0; g < 4; ++g)
                acc[g] = __builtin_amdgcn_mfma_f32_16x16x32_bf16(a, Bh[kf][g], acc[g], 0, 0, 0);
        }
        __syncthreads();   // MFMA reads done before h(t) writes

#pragma unroll
        for (int r = 0; r < 4; ++r) {
            float si = sigm_r(acc[0][r]);
            float sf = sigm_r(acc[1][r]);
            float tg = tanh_r(acc[2][r]);
            float so = sigm_r(acc[3][r]);
            float cs = sf * cst[r] + si * tg;
            cst[r] = cs;
            float h = so * tanh_r(cs);
            __hip_bfloat16 hb = fbf(h);
            int s = quad * 4 + r;
            int j = 16 * W + col;
            hA[s][j] = hb;
            if (t == 31) {
                n_f32[(size_t)(n0 + s) * 384 + j] = h;
                n_bf[(size_t)(n0 + s) * 384 + j] = hb;
            }
        }
    }
}

// ---------------- generic bf16 MFMA GEMM -----------------------------------
// C[M][N] = A[M][K] @ B[N][K]^T (+bias[col]); block tile 128Mx64N, wave 32Mx64N.
// flags: bit0 = bf16 out, bit1 = store transposed (C^T at [col][row], ldc=M)
//        bit2 = lstm-gx layout: row=n*32+t -> C[t][col][n] (slab 768x1024)
__global__ __launch_bounds__(256) void gemm_kernel(
    const __hip_bfloat16* __restrict__ A, long lda,
    const __hip_bfloat16* __restrict__ B, long ldb,
    const float* __restrict__ bias,
    void* __restrict__ C, long ldc, int K, int flags)
{
    const int tid = threadIdx.x;
    const int wv = tid >> 6, lane = tid & 63;
    const int col = lane & 15, quad = lane >> 4;
    const long m0 = (long)blockIdx.y * 128 + wv * 32;
    const long n0 = (long)blockIdx.x * 64;

    const __hip_bfloat16* Ap = A + (m0 + col) * lda + quad * 8;
    const __hip_bfloat16* Ap2 = Ap + 16 * lda;
    const __hip_bfloat16* Bp = B + (n0 + col) * ldb + quad * 8;

    f32x4 acc[2][4];
#pragma unroll
    for (int mt = 0; mt < 2; ++mt)
#pragma unroll
        for (int nt = 0; nt < 4; ++nt) acc[mt][nt] = (f32x4)0.0f;

#pragma unroll 4
    for (int k = 0; k < K; k += 32) {
        bf16x8 a0 = *(const bf16x8*)(Ap + k);
        bf16x8 a1 = *(const bf16x8*)(Ap2 + k);
#pragma unroll
        for (int nt = 0; nt < 4; ++nt) {
            bf16x8 b = *(const bf16x8*)(Bp + (long)nt * 16 * ldb + k);
            acc[0][nt] = __builtin_amdgcn_mfma_f32_16x16x32_bf16(a0, b, acc[0][nt], 0, 0, 0);
            acc[1][nt] = __builtin_amdgcn_mfma_f32_16x16x32_bf16(a1, b, acc[1][nt], 0, 0, 0);
        }
    }
#pragma unroll
    for (int mt = 0; mt < 2; ++mt)
#pragma unroll
        for (int nt = 0; nt < 4; ++nt)
#pragma unroll
            for (int r = 0; r < 4; ++r) {
                long row = m0 + mt * 16 + quad * 4 + r;
                long cc = n0 + nt * 16 + col;
                float v = acc[mt][nt][r] + (bias ? bias[cc] : 0.0f);
                if (flags & 4) {
                    ((__hip_bfloat16*)C)[(size_t)(row & 31) * 786432 + cc * 1024 + (row >> 5)] = fbf(v);
                } else if (flags & 2) {
                    if (flags & 1) ((__hip_bfloat16*)C)[cc * ldc + row] = fbf(v);
                    else           ((float*)C)[cc * ldc + row] = v;
                } else {
                    if (flags & 1) ((__hip_bfloat16*)C)[row * ldc + cc] = fbf(v);
                    else           ((float*)C)[row * ldc + cc] = v;
                }
            }
}

// ---------------- layer-2 backward single-step gates -----------------------
__global__ __launch_bounds__(256) void bwdgates_kernel(
    const float* __restrict__ g2b, float* __restrict__ n_f32,
    __hip_bfloat16* __restrict__ n_bf)
{
    int idx = blockIdx.x * 256 + threadIdx.x;   // < 196608
    int n = idx / 192, j = idx % 192;
    float gi_ = g2b[(size_t)n * 768 + j];
    float gg_ = g2b[(size_t)n * 768 + 384 + j];
    float go_ = g2b[(size_t)n * 768 + 576 + j];
    float c = sigm(gi_) * tanh_f(gg_);          // f-term has c0=0
    float h = sigm(go_) * tanh_f(c);
    n_f32[(size_t)n * 384 + 192 + j] = h;
    n_bf[(size_t)n * 384 + 192 + j] = fbf(h);
}

// ---------------- combine: n_k = G/S + A3 @ Wa + b --------------------------
__global__ __launch_bounds__(128) void comb_kernel(
    const float* __restrict__ G, const float* __restrict__ S,
    const float* __restrict__ A3, const float* __restrict__ Wa,   // [3][128]
    const float* __restrict__ bb, float* __restrict__ out_f,
    __hip_bfloat16* __restrict__ out_b)
{
    int y = blockIdx.x, o = threadIdx.x;
    float v = G[(size_t)y * 128 + o] / S[y]
            + A3[y * 3 + 0] * Wa[o] + A3[y * 3 + 1] * Wa[128 + o] + A3[y * 3 + 2] * Wa[256 + o]
            + bb[o];
    out_f[(size_t)y * 128 + o] = v;
    if (out_b) out_b[(size_t)y * 128 + o] = fbf(v);
}

// ---------------- final head -----------------------------------------------
__global__ __launch_bounds__(256) void final_kernel(
    const float* __restrict__ n_, const float* __restrict__ n1,
    const float* __restrict__ n2, const float* __restrict__ Wout,
    const float* __restrict__ bout, float* __restrict__ out)
{
    int y = blockIdx.x * 256 + threadIdx.x;
    if (y >= 1024) return;
    float a0 = bout[0], a1 = bout[1];
    for (int k = 0; k < 384; ++k) {
        float v = n_[(size_t)y * 384 + k];
        a0 += v * Wout[k * 2]; a1 += v * Wout[k * 2 + 1];
    }
    for (int k = 0; k < 128; ++k) {
        float v = n1[(size_t)y * 128 + k];
        a0 += v * Wout[(384 + k) * 2]; a1 += v * Wout[(384 + k) * 2 + 1];
    }
    for (int k = 0; k < 128; ++k) {
        float v = n2[(size_t)y * 128 + k];
        a0 += v * Wout[(512 + k) * 2]; a1 += v * Wout[(512 + k) * 2 + 1];
    }
    out[y * 2] = tanh_f(a0);
    out[y * 2 + 1] = tanh_f(a1);
}

// ---------------------------------------------------------------------------
extern "C" void kernel_launch(void* const* d_in, const int* in_sizes, int n_in,
                              void* d_out, int out_size, void* d_ws, size_t ws_size,
                              hipStream_t stream)
{
    const float* input  = (const float*)d_in[0];
    const float* theta  = (const float*)d_in[1];
    const float* all_PP = (const float*)d_in[2];
    const float* W_ih0  = (const float*)d_in[3];
    const float* W_hh0  = (const float*)d_in[4];
    const float* b_ih0  = (const float*)d_in[5];
    const float* b_hh0  = (const float*)d_in[6];
    const float* W_ih1  = (const float*)d_in[7];
    const float* W_hh1  = (const float*)d_in[8];
    const float* b_ih1  = (const float*)d_in[9];
    const float* b_hh1  = (const float*)d_in[10];
    const float* W_agg1 = (const float*)d_in[11];
    const float* b_agg1 = (const float*)d_in[12];
    const float* W_agg2 = (const float*)d_in[13];
    const float* b_agg2 = (const float*)d_in[14];
    const float* W_out  = (const float*)d_in[15];
    const float* b_out  = (const float*)d_in[16];
    float* out = (float*)d_out;

    char* ws = (char*)d_ws;
    size_t off = 0;
    auto alloc = [&](size_t bytes) -> char* {
        char* p = ws + off;
        off = (off + bytes + 255) & ~(size_t)255;
        return p;
    };
    __hip_bfloat16* Bpack0 = (__hip_bfloat16*)alloc(344064 * 2);
    __hip_bfloat16* Whh1f  = (__hip_bfloat16*)alloc(147456 * 2);
    __hip_bfloat16* Wih1f  = (__hip_bfloat16*)alloc(294912 * 2);
    __hip_bfloat16* Wih1b  = (__hip_bfloat16*)alloc(294912 * 2);
    __hip_bfloat16* Wf1t   = (__hip_bfloat16*)alloc(49152 * 2);
    __hip_bfloat16* Wf2t   = (__hip_bfloat16*)alloc(16384 * 2);
    float* bias0  = (float*)alloc(1536 * 4);
    float* bias1f = (float*)alloc(768 * 4);
    float* bias1b = (float*)alloc(768 * 4);
    int* pid  = (int*)alloc(1024 * 4);
    int* offv = (int*)alloc(1024 * 4);
    __hip_bfloat16* E_T = (__hip_bfloat16*)alloc((size_t)1024 * 1024 * 2);
    float* Sv  = (float*)alloc(1024 * 4);
    float* A3v = (float*)alloc(1024 * 3 * 4);
    __hip_bfloat16* h1  = (__hip_bfloat16*)alloc((size_t)1024 * 32 * 384 * 2);
    __hip_bfloat16* gx2 = (__hip_bfloat16*)alloc((size_t)32 * 768 * 1024 * 2);
    float* g2b = (float*)alloc((size_t)1024 * 768 * 4);
    float* n_f32 = (float*)alloc((size_t)1024 * 384 * 4);
    __hip_bfloat16* n_bf = (__hip_bfloat16*)alloc((size_t)1024 * 384 * 2);
    __hip_bfloat16* fWf1t = (__hip_bfloat16*)alloc((size_t)128 * 1024 * 2);
    float* G1 = (float*)alloc((size_t)1024 * 128 * 4);
    float* n1_f32 = (float*)alloc((size_t)1024 * 128 * 4);
    __hip_bfloat16* n1_bf = (__hip_bfloat16*)alloc((size_t)1024 * 128 * 2);
    __hip_bfloat16* fWf2t = (__hip_bfloat16*)alloc((size_t)128 * 1024 * 2);
    float* G2 = (float*)alloc((size_t)1024 * 128 * 4);
    float* n2_f32 = (float*)alloc((size_t)1024 * 128 * 4);
    (void)ws_size; (void)in_sizes; (void)n_in; (void)out_size;

    prep_kernel<<<(PA9 + 255) / 256, 256, 0, stream>>>(
        input, theta, W_ih0, W_hh0, b_ih0, b_hh0, W_ih1, W_hh1, b_ih1, b_hh1,
        W_agg1, W_agg2, Bpack0, Whh1f, Wih1f, Wih1b, Wf1t, Wf2t,
        bias0, bias1f, bias1b, pid, offv);

    dnbeta_kernel<<<1024, 256, 0, stream>>>(all_PP, pid, offv, E_T, Sv, A3v);

    lstm1_kernel<<<dim3(64, 2), 768, 0, stream>>>(input, Bpack0, bias0, h1);

    // gx2 = h1 @ Wih1_fwd^T + bias1f (M=32768,N=768,K=384) -> [t][col][n] bf16
    gemm_kernel<<<dim3(12, 256), 256, 0, stream>>>(h1, 384L, Wih1f, 384L, bias1f,
                                                   gx2, 0L, 384, 5);

    lstm2f_kernel<<<64, 768, 0, stream>>>(gx2, Whh1f, n_bf, n_f32);

    // layer2 bwd single step: g2b = h1[:,31,:] @ Wih1_bwd^T + bias1b
    gemm_kernel<<<dim3(12, 8), 256, 0, stream>>>(h1 + 31 * 384, 12288L, Wih1b, 384L,
                                                 bias1b, g2b, 768L, 384, 0);
    bwdgates_kernel<<<768, 256, 0, stream>>>(g2b, n_f32, n_bf);

    // fWf1^T = (n @ Wf1)^T   (M=1024, N=128, K=384) -> bf16 transposed [128][1024]
    gemm_kernel<<<dim3(2, 8), 256, 0, stream>>>(n_bf, 384L, Wf1t, 384L, nullptr,
                                                fWf1t, 1024L, 384, 3);
    // G1 = E^T @ fWf1        (M=1024, N=128, K=1024)
    gemm_kernel<<<dim3(2, 8), 256, 0, stream>>>(E_T, 1024L, fWf1t, 1024L, nullptr,
                                                G1, 128L, 1024, 0);
    comb_kernel<<<1024, 128, 0, stream>>>(G1, Sv, A3v, W_agg1 + 384 * 128, b_agg1,
                                          n1_f32, n1_bf);

    // fWf2^T = (n1 @ Wf2)^T  (M=1024, N=128, K=128)
    gemm_kernel<<<dim3(2, 8), 256, 0, stream>>>(n1_bf, 128L, Wf2t, 128L, nullptr,
                                                fWf2t, 1024L, 128, 3);
    // G2 = E^T @ fWf2
    gemm_kernel<<<dim3(2, 8), 256, 0, stream>>>(E_T, 1024L, fWf2t, 1024L, nullptr,
                                                G2, 128L, 1024, 0);
    comb_kernel<<<1024, 128, 0, stream>>>(G2, Sv, A3v, W_agg2 + 128 * 128, b_agg2,
                                          n2_f32, nullptr);

    final_kernel<<<4, 256, 0, stream>>>(n_f32, n1_f32, n2_f32, W_out, b_out, out);
}